// Round 6
// baseline (109.809 us; speedup 1.0000x reference)
//
#include <hip/hip_runtime.h>

// DynamicKoopmanOperator — R6: DIAGNOSTIC ROUND.
// Kernels byte-identical to R5 (64.7 us). The launcher dispatches the rollout
// TWICE (idempotent: reads x/coefdt only, rewrites identical bytes to d_out;
// serialized on the stream). dur - 64.7 = true rollout duration, resolving the
// MLP-vs-rollout split that rocprof's top-5 (all 150us harness fills) hides.

#define DT_CONST 0.01f

typedef float f32x4 __attribute__((ext_vector_type(4)));

constexpr int KDIM  = 256;
constexpr int KHALF = 128;   // k-split factor 2
constexpr int AROWS = 4;     // batch rows per MLP block  -> 256 blocks x 512 thr
constexpr int RROWS = 8;     // batch rows per rollout block (2 per wave)
constexpr int CHUNK = 32;    // timesteps per rollout block -> grid (128, 8)

// ---------------- Kernel A: MLP -> coefdt[b][k] = eig[b][k] * dt ------------
__global__ __launch_bounds__(512) void koopman_mlp(
    const float* __restrict__ x,  const float* __restrict__ W1,
    const float* __restrict__ b1, const float* __restrict__ W2,
    const float* __restrict__ b2, float* __restrict__ coefdt)
{
    __shared__ alignas(16) float part[2][AROWS][KDIM];  // 8 KiB partials
    __shared__ alignas(16) float hs[AROWS][KDIM];       // 4 KiB hidden

    const int tid = threadIdx.x;
    const int j   = tid & (KDIM - 1);       // output column 0..255
    const int kh  = tid >> 8;               // k-half 0/1 (wave-uniform)
    const int b0  = blockIdx.x * AROWS;

    float acc[AROWS];

    // GEMM 1 partial: k in [kh*128, kh*128+128)
    {
#pragma unroll
        for (int r = 0; r < AROWS; ++r) acc[r] = 0.f;
        const float* xb = x + (size_t)b0 * KDIM + kh * KHALF;  // uniform -> s_load
        const float* w  = W1 + (size_t)kh * KHALF * KDIM + j;
#pragma unroll 8
        for (int k = 0; k < KHALF; ++k) {
            float wk = w[(size_t)k * KDIM];        // coalesced, L2-resident
#pragma unroll
            for (int r = 0; r < AROWS; ++r)
                acc[r] = fmaf(xb[r * KDIM + k], wk, acc[r]);
        }
#pragma unroll
        for (int r = 0; r < AROWS; ++r) part[kh][r][j] = acc[r];
    }
    __syncthreads();
    if (kh == 0) {
#pragma unroll
        for (int r = 0; r < AROWS; ++r)
            hs[r][j] = tanhf(part[0][r][j] + part[1][r][j] + b1[j]);
    }
    __syncthreads();

    // GEMM 2 partial: h via uniform ds_read_b128 (broadcast, 4 k per read)
    {
#pragma unroll
        for (int r = 0; r < AROWS; ++r) acc[r] = 0.f;
        const float* w = W2 + (size_t)kh * KHALF * KDIM + j;
#pragma unroll 2
        for (int k4 = 0; k4 < KHALF / 4; ++k4) {
            f32x4 hv[AROWS];
#pragma unroll
            for (int r = 0; r < AROWS; ++r)
                hv[r] = *reinterpret_cast<const f32x4*>(&hs[r][kh * KHALF + k4 * 4]);
#pragma unroll
            for (int i = 0; i < 4; ++i) {
                float wk = w[(size_t)(k4 * 4 + i) * KDIM];
#pragma unroll
                for (int r = 0; r < AROWS; ++r)
                    acc[r] = fmaf(hv[r][i], wk, acc[r]);
            }
        }
#pragma unroll
        for (int r = 0; r < AROWS; ++r) part[kh][r][j] = acc[r];
    }
    __syncthreads();
    if (kh == 0) {
#pragma unroll
        for (int r = 0; r < AROWS; ++r)
            coefdt[(size_t)(b0 + r) * KDIM + j] =
                (part[0][r][j] + part[1][r][j] + b2[j]) * DT_CONST;
    }
}

// ---------------- Kernel B: rollout, 2 independent chains per wave ----------
__global__ __launch_bounds__(256) void koopman_rollout(
    const float* __restrict__ x, const float* __restrict__ coefdt,
    float* __restrict__ out, int T)
{
    const int wave = threadIdx.x >> 6;
    const int lane = threadIdx.x & 63;            // lane = 2 pairs (4 elems)
    const int bA   = blockIdx.x * RROWS + wave;   // chain A row
    const int bB   = bA + 4;                      // chain B row (independent)
    const int t0   = blockIdx.y * CHUNK;

    const f32x4 cA = *reinterpret_cast<const f32x4*>(coefdt + (size_t)bA * KDIM + lane * 4);
    const f32x4 xA = *reinterpret_cast<const f32x4*>(x      + (size_t)bA * KDIM + lane * 4);
    const f32x4 cB = *reinterpret_cast<const f32x4*>(coefdt + (size_t)bB * KDIM + lane * 4);
    const f32x4 xB = *reinterpret_cast<const f32x4*>(x      + (size_t)bB * KDIM + lane * 4);

    const float tf = (float)t0;
    float s, co, e;

    // seeds z = M^{t0} x (closed form) and per-step multipliers, chain A
    e = expf(cA.x * tf); sincosf(cA.y * tf, &s, &co);
    float zA0 = e * (co * xA.x - s * xA.y), zA1 = e * (s * xA.x + co * xA.y);
    e = expf(cA.z * tf); sincosf(cA.w * tf, &s, &co);
    float zA2 = e * (co * xA.z - s * xA.w), zA3 = e * (s * xA.z + co * xA.w);
    e = expf(cA.x); sincosf(cA.y, &s, &co);
    const float aA0 = e * co, gA0 = e * s;
    e = expf(cA.z); sincosf(cA.w, &s, &co);
    const float aA1 = e * co, gA1 = e * s;

    // chain B
    e = expf(cB.x * tf); sincosf(cB.y * tf, &s, &co);
    float zB0 = e * (co * xB.x - s * xB.y), zB1 = e * (s * xB.x + co * xB.y);
    e = expf(cB.z * tf); sincosf(cB.w * tf, &s, &co);
    float zB2 = e * (co * xB.z - s * xB.w), zB3 = e * (s * xB.z + co * xB.w);
    e = expf(cB.x); sincosf(cB.y, &s, &co);
    const float aB0 = e * co, gB0 = e * s;
    e = expf(cB.z); sincosf(cB.w, &s, &co);
    const float aB1 = e * co, gB1 = e * s;

    f32x4* oA = reinterpret_cast<f32x4*>(out + ((size_t)bA * T + t0) * KDIM) + lane;
    f32x4* oB = reinterpret_cast<f32x4*>(out + ((size_t)bB * T + t0) * KDIM) + lane;
    const int nt = ((t0 + CHUNK < T) ? CHUNK : (T - t0));
#pragma unroll 4
    for (int t = 0; t < nt; ++t) {
        float nA0 = aA0 * zA0 - gA0 * zA1;
        float nA1 = gA0 * zA0 + aA0 * zA1;
        float nA2 = aA1 * zA2 - gA1 * zA3;
        float nA3 = gA1 * zA2 + aA1 * zA3;
        float nB0 = aB0 * zB0 - gB0 * zB1;
        float nB1 = gB0 * zB0 + aB0 * zB1;
        float nB2 = aB1 * zB2 - gB1 * zB3;
        float nB3 = gB1 * zB2 + aB1 * zB3;
        f32x4 vA = { nA0, nA1, nA2, nA3 };
        f32x4 vB = { nB0, nB1, nB2, nB3 };
        *oA = vA;                                  // two independent 1 KiB
        *oB = vB;                                  // wave-stores back-to-back
        oA += KDIM / 4; oB += KDIM / 4;
        zA0 = nA0; zA1 = nA1; zA2 = nA2; zA3 = nA3;
        zB0 = nB0; zB1 = nB1; zB2 = nB2; zB3 = nB3;
    }
}

// ---------------- launcher ---------------------------------------------------
extern "C" void kernel_launch(void* const* d_in, const int* in_sizes, int n_in,
                              void* d_out, int out_size, void* d_ws, size_t ws_size,
                              hipStream_t stream) {
    const float* x  = (const float*)d_in[0];
    const float* W1 = (const float*)d_in[1];
    const float* b1 = (const float*)d_in[2];
    const float* W2 = (const float*)d_in[3];
    const float* b2 = (const float*)d_in[4];

    const int Kd = in_sizes[2];                 // 256
    const int Bb = in_sizes[0] / Kd;            // 1024
    const int T  = out_size / (Bb * Kd);        // 256

    float* coefdt = (float*)d_ws;               // B*K floats = 1 MiB
    float* out    = (float*)d_out;

    koopman_mlp<<<Bb / AROWS, 512, 0, stream>>>(x, W1, b1, W2, b2, coefdt);

    dim3 grid(Bb / RROWS, (T + CHUNK - 1) / CHUNK);
    // DIAGNOSTIC: rollout dispatched twice (idempotent, identical output).
    // dur - 64.7us isolates the rollout's standalone duration.
    koopman_rollout<<<grid, 256, 0, stream>>>(x, coefdt, out, T);
    koopman_rollout<<<grid, 256, 0, stream>>>(x, coefdt, out, T);
}

// Round 7
// 61.373 us; speedup vs baseline: 1.7892x; 1.7892x over previous
//
#include <hip/hip_runtime.h>

// DynamicKoopmanOperator — R7: FUSED single kernel.
// Diagnosis (R5/R6 A/B): rollout+gap = 45.1 us (~6.2 TB/s, near fill's 7.0);
// MLP+gap = 19.6 us vs ~4 us of actual work -> dispatch/drain overhead and/or
// latency-bound MLP phase. Fusion removes one launch + inter-kernel drain +
// coef global round-trip; MLP result passes through LDS.
//
// Structure: 256 blocks x 512 threads (1 block/CU, 8 waves/CU).
//   Phase 1 (R5's proven MLP): ksplit-2 over k-halves, 4 batch rows/block,
//     coef (pre-scaled by dt) -> LDS.
//   Phase 2: 8 waves = 4 rows x 2 T-halves, each seeded in closed form at
//     t0 in {0, T/2}; plain f32x4 stores (NT measured worse in R2).

#define DT_CONST 0.01f

typedef float f32x4 __attribute__((ext_vector_type(4)));

constexpr int KDIM  = 256;
constexpr int KHALF = 128;   // k-split factor 2
constexpr int AROWS = 4;     // batch rows per block -> 256 blocks

// ---------------- fused kernel ----------------------------------------------
__global__ __launch_bounds__(512, 4) void koopman_fused(
    const float* __restrict__ x,  const float* __restrict__ W1,
    const float* __restrict__ b1, const float* __restrict__ W2,
    const float* __restrict__ b2, float* __restrict__ out, int T)
{
    __shared__ alignas(16) float part[2][AROWS][KDIM];  // 8 KiB partials
    __shared__ alignas(16) float hs[AROWS][KDIM];       // 4 KiB hidden
    __shared__ alignas(16) float coef[AROWS][KDIM];     // 4 KiB eig*dt

    const int tid = threadIdx.x;
    const int j   = tid & (KDIM - 1);       // output column 0..255
    const int kh  = tid >> 8;               // k-half 0/1 (wave-uniform)
    const int b0  = blockIdx.x * AROWS;

    float acc[AROWS];

    // ---- Phase 1a: GEMM 1 partial, k in [kh*128, kh*128+128) ----
    {
#pragma unroll
        for (int r = 0; r < AROWS; ++r) acc[r] = 0.f;
        const float* xb = x + (size_t)b0 * KDIM + kh * KHALF;  // uniform -> s_load
        const float* w  = W1 + (size_t)kh * KHALF * KDIM + j;
#pragma unroll 8
        for (int k = 0; k < KHALF; ++k) {
            float wk = w[(size_t)k * KDIM];        // coalesced, L2-resident
#pragma unroll
            for (int r = 0; r < AROWS; ++r)
                acc[r] = fmaf(xb[r * KDIM + k], wk, acc[r]);
        }
#pragma unroll
        for (int r = 0; r < AROWS; ++r) part[kh][r][j] = acc[r];
    }
    __syncthreads();
    if (kh == 0) {
#pragma unroll
        for (int r = 0; r < AROWS; ++r)
            hs[r][j] = tanhf(part[0][r][j] + part[1][r][j] + b1[j]);
    }
    __syncthreads();

    // ---- Phase 1b: GEMM 2 partial, h via uniform ds_read_b128 ----
    {
#pragma unroll
        for (int r = 0; r < AROWS; ++r) acc[r] = 0.f;
        const float* w = W2 + (size_t)kh * KHALF * KDIM + j;
#pragma unroll 2
        for (int k4 = 0; k4 < KHALF / 4; ++k4) {
            f32x4 hv[AROWS];
#pragma unroll
            for (int r = 0; r < AROWS; ++r)
                hv[r] = *reinterpret_cast<const f32x4*>(&hs[r][kh * KHALF + k4 * 4]);
#pragma unroll
            for (int i = 0; i < 4; ++i) {
                float wk = w[(size_t)(k4 * 4 + i) * KDIM];
#pragma unroll
                for (int r = 0; r < AROWS; ++r)
                    acc[r] = fmaf(hv[r][i], wk, acc[r]);
            }
        }
#pragma unroll
        for (int r = 0; r < AROWS; ++r) part[kh][r][j] = acc[r];
    }
    __syncthreads();
    if (kh == 0) {
#pragma unroll
        for (int r = 0; r < AROWS; ++r)
            coef[r][j] = (part[0][r][j] + part[1][r][j] + b2[j]) * DT_CONST;
    }
    __syncthreads();

    // ---- Phase 2: rollout. wave -> (row, T-half); closed-form seed ----
    const int wave = tid >> 6;              // 0..7
    const int lane = tid & 63;              // lane = 2 pairs (4 elems)
    const int r    = wave & (AROWS - 1);    // row within block
    const int tseg = wave >> 2;             // 0/1
    const int b    = b0 + r;
    const int tlen = (T + 1) >> 1;          // 128
    const int t0   = tseg * tlen;

    const f32x4 c  = *reinterpret_cast<const f32x4*>(&coef[r][lane * 4]);
    const f32x4 xv = *reinterpret_cast<const f32x4*>(x + (size_t)b * KDIM + lane * 4);
    // c = (mu0*dt, om0*dt, mu1*dt, om1*dt)

    // seed z = M^{t0} x  (t0=0: exp(0)=1, sincos(0)=(0,1) -> z = x exactly)
    const float tf = (float)t0;
    float s, co, e;
    e = expf(c.x * tf); sincosf(c.y * tf, &s, &co);
    float z0 = e * (co * xv.x - s * xv.y);
    float z1 = e * (s * xv.x + co * xv.y);
    e = expf(c.z * tf); sincosf(c.w * tf, &s, &co);
    float z2 = e * (co * xv.z - s * xv.w);
    float z3 = e * (s * xv.z + co * xv.w);

    // per-step multipliers
    e = expf(c.x); sincosf(c.y, &s, &co);
    const float a0 = e * co, g0 = e * s;
    e = expf(c.z); sincosf(c.w, &s, &co);
    const float a1 = e * co, g1 = e * s;

    f32x4* orow = reinterpret_cast<f32x4*>(out + ((size_t)b * T + t0) * KDIM) + lane;
    const int nt = ((t0 + tlen < T) ? tlen : (T - t0));
#pragma unroll 4
    for (int t = 0; t < nt; ++t) {
        float n0 = a0 * z0 - g0 * z1;
        float n1 = g0 * z0 + a0 * z1;
        float n2 = a1 * z2 - g1 * z3;
        float n3 = g1 * z2 + a1 * z3;
        f32x4 v = { n0, n1, n2, n3 };
        *orow = v;                           // plain store, through L2
        orow += KDIM / 4;                    // next timestep, 1 KiB row/wave
        z0 = n0; z1 = n1; z2 = n2; z3 = n3;
    }
}

// ---------------- launcher ---------------------------------------------------
extern "C" void kernel_launch(void* const* d_in, const int* in_sizes, int n_in,
                              void* d_out, int out_size, void* d_ws, size_t ws_size,
                              hipStream_t stream) {
    const float* x  = (const float*)d_in[0];
    const float* W1 = (const float*)d_in[1];
    const float* b1 = (const float*)d_in[2];
    const float* W2 = (const float*)d_in[3];
    const float* b2 = (const float*)d_in[4];

    const int Kd = in_sizes[2];                 // 256
    const int Bb = in_sizes[0] / Kd;            // 1024
    const int T  = out_size / (Bb * Kd);        // 256

    float* out = (float*)d_out;

    koopman_fused<<<Bb / AROWS, 512, 0, stream>>>(x, W1, b1, W2, b2, out, T);
}